// Round 1
// baseline (385.155 us; speedup 1.0000x reference)
//
#include <hip/hip_runtime.h>
#include <hip/hip_bf16.h>
#include <cstdint>
#include <cstddef>

static constexpr int T_TOK = 8192;   // B*S
static constexpr int D_DIM = 768;
static constexpr int E_NUM = 8;
static constexpr int F_DIM = 3072;
static constexpr int MAX_TILES = 72; // 8 XCD groups x 9 m-tiles; sum ceil(cnt/128) <= 71

typedef __attribute__((ext_vector_type(8))) short short8;
typedef __attribute__((ext_vector_type(4))) float floatx4;
typedef __attribute__((ext_vector_type(8))) unsigned short ushort8v;

__device__ __forceinline__ void async16(const void* g, void* l) {
  __builtin_amdgcn_global_load_lds(
      (const __attribute__((address_space(1))) unsigned int*)g,
      (__attribute__((address_space(3))) unsigned int*)l, 16, 0, 0);
}

// gelu tanh-approx in sigmoid form: x*sigmoid(1.59577x + 0.0713548x^3)
// max dev vs exact erf-gelu ~3e-4 (absmax headroom 4.8x)
__device__ __forceinline__ float gelu_fast(float v) {
  float s = v * (1.5957691f + 0.071354813f * v * v);
  return v / (1.0f + __expf(-s));
}

// ---------------- gate: logits fp32, argmax, fused x->bf16. NO atomics. ------
__global__ __launch_bounds__(256)
void gate_kernel(const float* __restrict__ x, const float* __restrict__ gw,
                 const float* __restrict__ gb, int* __restrict__ expert_idx,
                 __hip_bfloat16* __restrict__ xb) {
  int gid = blockIdx.x * blockDim.x + threadIdx.x;
  int tok = gid >> 6;
  int lane = threadIdx.x & 63;
  if (tok >= T_TOK) return;
  const float* xr = x + (size_t)tok * D_DIM;
  __hip_bfloat16* xbr = xb + (size_t)tok * D_DIM;
  float acc[8];
#pragma unroll
  for (int e = 0; e < 8; e++) acc[e] = 0.f;
#pragma unroll
  for (int i = 0; i < D_DIM / 64; i++) {
    int d = lane + i * 64;
    float v = xr[d];
    xbr[d] = __float2bfloat16(v);
    const float4* g4 = (const float4*)(gw + (size_t)d * 8);
    float4 a = g4[0], b = g4[1];
    acc[0] += v * a.x; acc[1] += v * a.y; acc[2] += v * a.z; acc[3] += v * a.w;
    acc[4] += v * b.x; acc[5] += v * b.y; acc[6] += v * b.z; acc[7] += v * b.w;
  }
#pragma unroll
  for (int e = 0; e < 8; e++) {
#pragma unroll
    for (int o = 32; o > 0; o >>= 1) acc[e] += __shfl_xor(acc[e], o, 64);
  }
  if (lane == 0) {
    int best = 0;
    float bv = acc[0] + gb[0];
#pragma unroll
    for (int e = 1; e < 8; e++) {
      float v = acc[e] + gb[e];
      if (v > bv) { bv = v; best = e; }  // strict > == np.argmax tie-break
    }
    expert_idx[tok] = best;
  }
}

// ---------------- count: LDS histogram, 8 global atomics per block ----------
__global__ __launch_bounds__(256)
void count_kernel(const int* __restrict__ expert_idx, int* __restrict__ counts) {
  __shared__ int h[E_NUM];
  if (threadIdx.x < E_NUM) h[threadIdx.x] = 0;
  __syncthreads();
  int t = blockIdx.x * blockDim.x + threadIdx.x;
  if (t < T_TOK) atomicAdd(&h[expert_idx[t]], 1);
  __syncthreads();
  if (threadIdx.x < E_NUM && h[threadIdx.x] > 0)
    atomicAdd(&counts[threadIdx.x], h[threadIdx.x]);
}

// ---------------- offsets + compact tile table ----------------
__global__ void offsets_kernel(const int* __restrict__ counts, int* __restrict__ offs,
                               int* __restrict__ meta) {
  if (threadIdx.x == 0) {
    int s = 0, tc = 0;
    for (int e = 0; e < E_NUM; e++) {
      offs[e] = s;
      int cnt = counts[e];
      for (int m = 0; m * 128 < cnt; m++) {
        meta[1 + tc] = e;
        meta[1 + MAX_TILES + tc] = m;
        tc++;
      }
      s += cnt;
    }
    offs[E_NUM] = s;
    meta[0] = tc;
  }
}

// ---------------- scatter: LDS ranks + block-aggregated global base --------
__global__ __launch_bounds__(256)
void scatter_kernel(const int* __restrict__ expert_idx, const int* __restrict__ offs,
                    int* __restrict__ fill, int* __restrict__ perm) {
  __shared__ int lcnt[E_NUM];
  __shared__ int lbase[E_NUM];
  if (threadIdx.x < E_NUM) lcnt[threadIdx.x] = 0;
  __syncthreads();
  int t = blockIdx.x * blockDim.x + threadIdx.x;
  int e = -1, rank = 0;
  if (t < T_TOK) {
    e = expert_idx[t];
    rank = atomicAdd(&lcnt[e], 1);   // LDS atomic: per-CU, cheap
  }
  __syncthreads();
  if (threadIdx.x < E_NUM)
    lbase[threadIdx.x] = (lcnt[threadIdx.x] > 0)
                           ? atomicAdd(&fill[threadIdx.x], lcnt[threadIdx.x]) : 0;
  __syncthreads();
  if (t < T_TOK) perm[offs[e] + lbase[e] + rank] = t;
}

// ---------------- weight transpose + cast: in [R][C] fp32 -> out [C][R] bf16 ----
__global__ __launch_bounds__(256)
void transpose_bf16(const float* __restrict__ in, __hip_bfloat16* __restrict__ out,
                    int R, int C) {
  __shared__ float t[64][65];
  const float* src = in + (size_t)blockIdx.z * R * C;
  __hip_bfloat16* dst = out + (size_t)blockIdx.z * R * C;
  int r0 = blockIdx.y * 64, c0 = blockIdx.x * 64;
  int tx = threadIdx.x & 15;
  int ty = threadIdx.x >> 4;
#pragma unroll
  for (int p = 0; p < 4; p++) {
    int r = ty + p * 16;
    float4 v = *(const float4*)&src[(size_t)(r0 + r) * C + c0 + tx * 4];
    t[tx * 4 + 0][r] = v.x; t[tx * 4 + 1][r] = v.y;
    t[tx * 4 + 2][r] = v.z; t[tx * 4 + 3][r] = v.w;
  }
  __syncthreads();
  int j = threadIdx.x & 7;
#pragma unroll
  for (int p = 0; p < 2; p++) {
    int cc = (threadIdx.x >> 3) + p * 32;
    __align__(16) __hip_bfloat16 tmp[8];
#pragma unroll
    for (int i = 0; i < 8; i++) tmp[i] = __float2bfloat16(t[cc][j * 8 + i]);
    *(ushort8v*)&dst[(size_t)(c0 + cc) * R + r0 + j * 8] = *(const ushort8v*)tmp;
  }
}

// ---------------- unified MoE GEMM: 128x128 tile, BK=64, double-buffered LDS ----
// 2-phase prefetch: stage(t+1) issued BEFORE compute(t); counted vmcnt(8) keeps
// next tile's 8 global_load_lds in flight across barriers (raw s_barrier, NOT
// __syncthreads which would drain vmcnt to 0 = the old 16% MfmaUtil mechanism).
// FIRST=true:  H[perm-order] = gelu(xb_gathered @ w1t^T + b1)   (K=768,  N=3072)
// FIRST=false: Out[perm]     = H @ w2t^T + b2                   (K=3072, N=768)
template<int K, int N, bool FIRST>
__global__ __launch_bounds__(256)
void moe_gemm(const __hip_bfloat16* __restrict__ A,
              const __hip_bfloat16* __restrict__ Bt,
              const float* __restrict__ bias,
              const int* __restrict__ meta,
              const int* __restrict__ offs,
              const int* __restrict__ perm,
              void* __restrict__ OutP) {
  int g = blockIdx.x;
  int xcd = g & 7;
  int j = g >> 3;
  int mt = xcd * 9 + (j % 9);
  int nt = j / 9;
  if (mt >= meta[0]) return;
  int e = meta[1 + mt];
  int m0 = meta[1 + MAX_TILES + mt] * 128;
  int off = offs[e], cnt = offs[e + 1] - off;
  int n0 = nt * 128;

  // [buf][ks][128 rows][32 bf16], 2 bufs x 2 ks x 8 KB = 32 KB each for A and B
  __shared__ __align__(16) __hip_bfloat16 As[2 * 8192];
  __shared__ __align__(16) __hip_bfloat16 Bs[2 * 8192];

  int tid = threadIdx.x, lane = tid & 63, w = tid >> 6;
  int lr0 = w * 32 + (lane >> 2), lr1 = lr0 + 16;
  int ch = (lane & 3) ^ ((lane >> 3) & 3);   // pre-swizzled global source, linear LDS

  int r0 = m0 + lr0; if (r0 > cnt - 1) r0 = cnt - 1;
  int r1 = m0 + lr1; if (r1 > cnt - 1) r1 = cnt - 1;
  const __hip_bfloat16* a0;
  const __hip_bfloat16* a1;
  if constexpr (FIRST) {
    a0 = A + (size_t)perm[off + r0] * K + ch * 8;
    a1 = A + (size_t)perm[off + r1] * K + ch * 8;
  } else {
    a0 = A + (size_t)(off + r0) * K + ch * 8;
    a1 = A + (size_t)(off + r1) * K + ch * 8;
  }
  const __hip_bfloat16* Bbase = Bt + ((size_t)e * N + n0) * K;
  const __hip_bfloat16* bp0 = Bbase + (size_t)lr0 * K + ch * 8;
  const __hip_bfloat16* bp1 = Bbase + (size_t)lr1 * K + ch * 8;

  int wr = (w >> 1) * 64, wc = (w & 1) * 64;
  int mrow = lane & 15, cq = lane >> 4;
  int aoff[4], boff[4];
#pragma unroll
  for (int i = 0; i < 4; i++) {
    int rr = wr + i * 16 + mrow;
    aoff[i] = rr * 32 + ((cq ^ ((rr >> 1) & 3)) * 8);
    int rb = wc + i * 16 + mrow;
    boff[i] = rb * 32 + ((cq ^ ((rb >> 1) & 3)) * 8);
  }

  auto stage = [&](int buf, int kk) {
#pragma unroll
    for (int ks = 0; ks < 2; ks++) {
      int ko = kk + ks * 32;
      __hip_bfloat16* la = &As[buf * 8192 + ks * 4096];
      __hip_bfloat16* lb = &Bs[buf * 8192 + ks * 4096];
      async16(a0 + ko, la + (w * 32) * 32);
      async16(a1 + ko, la + (w * 32 + 16) * 32);
      async16(bp0 + ko, lb + (w * 32) * 32);
      async16(bp1 + ko, lb + (w * 32 + 16) * 32);
    }
  };

  floatx4 acc[4][4];
#pragma unroll
  for (int i = 0; i < 4; i++)
#pragma unroll
    for (int jj = 0; jj < 4; jj++) acc[i][jj] = (floatx4){0.f, 0.f, 0.f, 0.f};

  constexpr int NT = K / 64;
  stage(0, 0);
  int p = 0;
  for (int t = 0; t < NT; ++t) {
    if (t + 1 < NT) {
      stage(p ^ 1, (t + 1) * 64);
      // wait only for tile t's 8 loads; tile t+1's 8 stay in flight
      asm volatile("s_waitcnt vmcnt(8)" ::: "memory");
    } else {
      asm volatile("s_waitcnt vmcnt(0)" ::: "memory");
    }
    __builtin_amdgcn_s_barrier();
    __builtin_amdgcn_sched_barrier(0);  // keep ds_reads below the barrier
#pragma unroll
    for (int ks = 0; ks < 2; ks++) {
      int lb = p * 8192 + ks * 4096;
      short8 af[4], bfv[4];
#pragma unroll
      for (int i = 0; i < 4; i++) af[i] = *(const short8*)&As[lb + aoff[i]];
#pragma unroll
      for (int i = 0; i < 4; i++) bfv[i] = *(const short8*)&Bs[lb + boff[i]];
#pragma unroll
      for (int mi = 0; mi < 4; mi++)
#pragma unroll
        for (int ni = 0; ni < 4; ni++)
          acc[mi][ni] = __builtin_amdgcn_mfma_f32_16x16x32_bf16(af[mi], bfv[ni], acc[mi][ni], 0, 0, 0);
    }
    __builtin_amdgcn_sched_barrier(0);  // keep ds_reads above the barrier
    __builtin_amdgcn_s_barrier();       // all waves done reading buf[p] before it's re-staged
    p ^= 1;
  }

#pragma unroll
  for (int mi = 0; mi < 4; mi++) {
    int rowl = wr + mi * 16 + (lane >> 4) * 4;
#pragma unroll
    for (int ni = 0; ni < 4; ni++) {
      int col = n0 + wc + ni * 16 + (lane & 15);
      float bia = bias[(size_t)e * N + col];
#pragma unroll
      for (int r = 0; r < 4; r++) {
        int gm = m0 + rowl + r;
        if (gm < cnt) {
          if constexpr (FIRST) {
            ((__hip_bfloat16*)OutP)[(size_t)(off + gm) * N + col] =
                __float2bfloat16(gelu_fast(acc[mi][ni][r] + bia));
          } else {
            ((float*)OutP)[(size_t)perm[off + gm] * N + col] = acc[mi][ni][r] + bia;
          }
        }
      }
    }
  }
}

extern "C" void kernel_launch(void* const* d_in, const int* in_sizes, int n_in,
                              void* d_out, int out_size, void* d_ws, size_t ws_size,
                              hipStream_t stream) {
  const float* x  = (const float*)d_in[0];
  const float* gw = (const float*)d_in[1];
  const float* gb = (const float*)d_in[2];
  const float* w1 = (const float*)d_in[3];
  const float* b1 = (const float*)d_in[4];
  const float* w2 = (const float*)d_in[5];
  const float* b2 = (const float*)d_in[6];
  float* out = (float*)d_out;

  char* ws = (char*)d_ws;
  int* counts = (int*)(ws + 0);
  int* fill   = (int*)(ws + 32);
  int* offs   = (int*)(ws + 64);
  int* meta   = (int*)(ws + 128);   // 145 ints
  int* eidx   = (int*)(ws + 1024);
  int* perm   = (int*)(ws + 1024 + 4 * T_TOK);
  size_t off = 1024 + 8 * (size_t)T_TOK;
  __hip_bfloat16* xb  = (__hip_bfloat16*)(ws + off); off += (size_t)T_TOK * D_DIM * 2;
  __hip_bfloat16* w1t = (__hip_bfloat16*)(ws + off); off += (size_t)E_NUM * D_DIM * F_DIM * 2;
  __hip_bfloat16* w2t = (__hip_bfloat16*)(ws + off); off += (size_t)E_NUM * D_DIM * F_DIM * 2;
  __hip_bfloat16* H   = (__hip_bfloat16*)(ws + off); off += (size_t)T_TOK * F_DIM * 2;

  hipMemsetAsync(d_ws, 0, 64, stream);  // counts + fill
  gate_kernel<<<T_TOK / 4, 256, 0, stream>>>(x, gw, gb, eidx, xb);
  count_kernel<<<T_TOK / 256, 256, 0, stream>>>(eidx, counts);
  offsets_kernel<<<1, 64, 0, stream>>>(counts, offs, meta);
  scatter_kernel<<<T_TOK / 256, 256, 0, stream>>>(eidx, offs, fill, perm);
  transpose_bf16<<<dim3(F_DIM / 64, D_DIM / 64, E_NUM), 256, 0, stream>>>(w1, w1t, D_DIM, F_DIM);
  transpose_bf16<<<dim3(D_DIM / 64, F_DIM / 64, E_NUM), 256, 0, stream>>>(w2, w2t, F_DIM, D_DIM);
  moe_gemm<D_DIM, F_DIM, true><<<8 * 9 * (F_DIM / 128), 256, 0, stream>>>(
      xb, w1t, b1, meta, offs, perm, (void*)H);
  moe_gemm<F_DIM, D_DIM, false><<<8 * 9 * (D_DIM / 128), 256, 0, stream>>>(
      H, w2t, b2, meta, offs, perm, (void*)out);
}

// Round 5
// 382.526 us; speedup vs baseline: 1.0069x; 1.0069x over previous
//
#include <hip/hip_runtime.h>
#include <hip/hip_bf16.h>
#include <cstdint>
#include <cstddef>

static constexpr int T_TOK = 8192;   // B*S
static constexpr int D_DIM = 768;
static constexpr int E_NUM = 8;
static constexpr int F_DIM = 3072;
static constexpr int MAX_TILES = 72; // 8 XCD groups x 9 m-tiles; sum ceil(cnt/128) <= 71

typedef __attribute__((ext_vector_type(8))) short short8;
typedef __attribute__((ext_vector_type(4))) float floatx4;
typedef __attribute__((ext_vector_type(8))) unsigned short ushort8v;

__device__ __forceinline__ void async16(const void* g, void* l) {
  __builtin_amdgcn_global_load_lds(
      (const __attribute__((address_space(1))) unsigned int*)g,
      (__attribute__((address_space(3))) unsigned int*)l, 16, 0, 0);
}

// gelu tanh-approx in sigmoid form: x*sigmoid(1.59577x + 0.0713548x^3)
// max dev vs exact erf-gelu ~3e-4 (absmax headroom 4.8x)
__device__ __forceinline__ float gelu_fast(float v) {
  float s = v * (1.5957691f + 0.071354813f * v * v);
  return v / (1.0f + __expf(-s));
}

// ---------------- gate: logits fp32, argmax, fused x->bf16. NO atomics. ------
__global__ __launch_bounds__(256)
void gate_kernel(const float* __restrict__ x, const float* __restrict__ gw,
                 const float* __restrict__ gb, int* __restrict__ expert_idx,
                 __hip_bfloat16* __restrict__ xb) {
  int gid = blockIdx.x * blockDim.x + threadIdx.x;
  int tok = gid >> 6;
  int lane = threadIdx.x & 63;
  if (tok >= T_TOK) return;
  const float* xr = x + (size_t)tok * D_DIM;
  __hip_bfloat16* xbr = xb + (size_t)tok * D_DIM;
  float acc[8];
#pragma unroll
  for (int e = 0; e < 8; e++) acc[e] = 0.f;
#pragma unroll
  for (int i = 0; i < D_DIM / 64; i++) {
    int d = lane + i * 64;
    float v = xr[d];
    xbr[d] = __float2bfloat16(v);
    const float4* g4 = (const float4*)(gw + (size_t)d * 8);
    float4 a = g4[0], b = g4[1];
    acc[0] += v * a.x; acc[1] += v * a.y; acc[2] += v * a.z; acc[3] += v * a.w;
    acc[4] += v * b.x; acc[5] += v * b.y; acc[6] += v * b.z; acc[7] += v * b.w;
  }
#pragma unroll
  for (int e = 0; e < 8; e++) {
#pragma unroll
    for (int o = 32; o > 0; o >>= 1) acc[e] += __shfl_xor(acc[e], o, 64);
  }
  if (lane == 0) {
    int best = 0;
    float bv = acc[0] + gb[0];
#pragma unroll
    for (int e = 1; e < 8; e++) {
      float v = acc[e] + gb[e];
      if (v > bv) { bv = v; best = e; }  // strict > == np.argmax tie-break
    }
    expert_idx[tok] = best;
  }
}

// ---------------- count: LDS histogram, 8 global atomics per block ----------
__global__ __launch_bounds__(256)
void count_kernel(const int* __restrict__ expert_idx, int* __restrict__ counts) {
  __shared__ int h[E_NUM];
  if (threadIdx.x < E_NUM) h[threadIdx.x] = 0;
  __syncthreads();
  int t = blockIdx.x * blockDim.x + threadIdx.x;
  if (t < T_TOK) atomicAdd(&h[expert_idx[t]], 1);
  __syncthreads();
  if (threadIdx.x < E_NUM && h[threadIdx.x] > 0)
    atomicAdd(&counts[threadIdx.x], h[threadIdx.x]);
}

// ---------------- offsets + compact tile table ----------------
__global__ void offsets_kernel(const int* __restrict__ counts, int* __restrict__ offs,
                               int* __restrict__ meta) {
  if (threadIdx.x == 0) {
    int s = 0, tc = 0;
    for (int e = 0; e < E_NUM; e++) {
      offs[e] = s;
      int cnt = counts[e];
      for (int m = 0; m * 128 < cnt; m++) {
        meta[1 + tc] = e;
        meta[1 + MAX_TILES + tc] = m;
        tc++;
      }
      s += cnt;
    }
    offs[E_NUM] = s;
    meta[0] = tc;
  }
}

// ---------------- scatter: LDS ranks + block-aggregated global base --------
__global__ __launch_bounds__(256)
void scatter_kernel(const int* __restrict__ expert_idx, const int* __restrict__ offs,
                    int* __restrict__ fill, int* __restrict__ perm) {
  __shared__ int lcnt[E_NUM];
  __shared__ int lbase[E_NUM];
  if (threadIdx.x < E_NUM) lcnt[threadIdx.x] = 0;
  __syncthreads();
  int t = blockIdx.x * blockDim.x + threadIdx.x;
  int e = -1, rank = 0;
  if (t < T_TOK) {
    e = expert_idx[t];
    rank = atomicAdd(&lcnt[e], 1);   // LDS atomic: per-CU, cheap
  }
  __syncthreads();
  if (threadIdx.x < E_NUM)
    lbase[threadIdx.x] = (lcnt[threadIdx.x] > 0)
                           ? atomicAdd(&fill[threadIdx.x], lcnt[threadIdx.x]) : 0;
  __syncthreads();
  if (t < T_TOK) perm[offs[e] + lbase[e] + rank] = t;
}

// ---------------- weight transpose + cast: in [R][C] fp32 -> out [C][R] bf16 ----
__global__ __launch_bounds__(256)
void transpose_bf16(const float* __restrict__ in, __hip_bfloat16* __restrict__ out,
                    int R, int C) {
  __shared__ float t[64][65];
  const float* src = in + (size_t)blockIdx.z * R * C;
  __hip_bfloat16* dst = out + (size_t)blockIdx.z * R * C;
  int r0 = blockIdx.y * 64, c0 = blockIdx.x * 64;
  int tx = threadIdx.x & 15;
  int ty = threadIdx.x >> 4;
#pragma unroll
  for (int p = 0; p < 4; p++) {
    int r = ty + p * 16;
    float4 v = *(const float4*)&src[(size_t)(r0 + r) * C + c0 + tx * 4];
    t[tx * 4 + 0][r] = v.x; t[tx * 4 + 1][r] = v.y;
    t[tx * 4 + 2][r] = v.z; t[tx * 4 + 3][r] = v.w;
  }
  __syncthreads();
  int j = threadIdx.x & 7;
#pragma unroll
  for (int p = 0; p < 2; p++) {
    int cc = (threadIdx.x >> 3) + p * 32;
    __align__(16) __hip_bfloat16 tmp[8];
#pragma unroll
    for (int i = 0; i < 8; i++) tmp[i] = __float2bfloat16(t[cc][j * 8 + i]);
    *(ushort8v*)&dst[(size_t)(c0 + cc) * R + r0 + j * 8] = *(const ushort8v*)tmp;
  }
}

// ---------------- unified MoE GEMM: 128x128 tile, BK=32, 3-slot ring, depth-2 ----
// Base = R1's PASSING kernel. Only change: 2-slot/BK=64/depth-1 -> 3-slot/BK=32/
// depth-2. stage() body, fragment offsets, handshake, epilogue are R1-verbatim.
// vmcnt(8) = tiles t+1,t+2 (4 loads each) stay in flight; tile t guaranteed
// landed. Slot (t+2)%3 was last read at iter t-1, and all waves passed iter
// t-1's trailing barrier before any wave issues stage(t+2) at iter t.
// FIRST=true:  H[perm-order] = gelu(xb_gathered @ w1t^T + b1)   (K=768,  N=3072)
// FIRST=false: Out[perm]     = H @ w2t^T + b2                   (K=3072, N=768)
template<int K, int N, bool FIRST>
__global__ __launch_bounds__(256)
void moe_gemm(const __hip_bfloat16* __restrict__ A,
              const __hip_bfloat16* __restrict__ Bt,
              const float* __restrict__ bias,
              const int* __restrict__ meta,
              const int* __restrict__ offs,
              const int* __restrict__ perm,
              void* __restrict__ OutP) {
  int g = blockIdx.x;
  int xcd = g & 7;
  int j = g >> 3;
  int mt = xcd * 9 + (j % 9);
  int nt = j / 9;
  if (mt >= meta[0]) return;
  int e = meta[1 + mt];
  int m0 = meta[1 + MAX_TILES + mt] * 128;
  int off = offs[e], cnt = offs[e + 1] - off;
  int n0 = nt * 128;

  // 3 slots x [128 rows][32 k] bf16 = 8 KB each; A 24 KB + B 24 KB = 48 KB
  __shared__ __align__(16) __hip_bfloat16 As[3 * 4096];
  __shared__ __align__(16) __hip_bfloat16 Bs[3 * 4096];

  int tid = threadIdx.x, lane = tid & 63, w = tid >> 6;
  int lr0 = w * 32 + (lane >> 2), lr1 = lr0 + 16;
  int ch = (lane & 3) ^ ((lane >> 3) & 3);   // pre-swizzled global source, linear LDS

  int r0 = m0 + lr0; if (r0 > cnt - 1) r0 = cnt - 1;
  int r1 = m0 + lr1; if (r1 > cnt - 1) r1 = cnt - 1;
  const __hip_bfloat16* a0;
  const __hip_bfloat16* a1;
  if constexpr (FIRST) {
    a0 = A + (size_t)perm[off + r0] * K + ch * 8;
    a1 = A + (size_t)perm[off + r1] * K + ch * 8;
  } else {
    a0 = A + (size_t)(off + r0) * K + ch * 8;
    a1 = A + (size_t)(off + r1) * K + ch * 8;
  }
  const __hip_bfloat16* Bbase = Bt + ((size_t)e * N + n0) * K;
  const __hip_bfloat16* bp0 = Bbase + (size_t)lr0 * K + ch * 8;
  const __hip_bfloat16* bp1 = Bbase + (size_t)lr1 * K + ch * 8;

  int wr = (w >> 1) * 64, wc = (w & 1) * 64;
  int mrow = lane & 15, cq = lane >> 4;
  int aoff[4], boff[4];
#pragma unroll
  for (int i = 0; i < 4; i++) {
    int rr = wr + i * 16 + mrow;
    aoff[i] = rr * 32 + ((cq ^ ((rr >> 1) & 3)) * 8);
    int rb = wc + i * 16 + mrow;
    boff[i] = rb * 32 + ((cq ^ ((rb >> 1) & 3)) * 8);
  }

  // one BK=32 sub-tile: 4 global_load_lds (R1's per-ks body verbatim)
  auto stage = [&](int slot, int ko) {
    __hip_bfloat16* la = &As[slot * 4096];
    __hip_bfloat16* lb = &Bs[slot * 4096];
    async16(a0 + ko, la + (w * 32) * 32);
    async16(a1 + ko, la + (w * 32 + 16) * 32);
    async16(bp0 + ko, lb + (w * 32) * 32);
    async16(bp1 + ko, lb + (w * 32 + 16) * 32);
  };

  floatx4 acc[4][4];
#pragma unroll
  for (int i = 0; i < 4; i++)
#pragma unroll
    for (int jj = 0; jj < 4; jj++) acc[i][jj] = (floatx4){0.f, 0.f, 0.f, 0.f};

  constexpr int NT = K / 32;
  stage(0, 0);
  stage(1, 32);
  for (int t = 0; t < NT; ++t) {
    if (t + 2 < NT) {
      stage((t + 2) % 3, (t + 2) * 32);
      // outstanding <= 12 (tiles t,t+1,t+2); wait to 8 -> tile t landed
      asm volatile("s_waitcnt vmcnt(8)" ::: "memory");
    } else if (t + 1 < NT) {
      asm volatile("s_waitcnt vmcnt(4)" ::: "memory");
    } else {
      asm volatile("s_waitcnt vmcnt(0)" ::: "memory");
    }
    __builtin_amdgcn_s_barrier();
    __builtin_amdgcn_sched_barrier(0);  // keep ds_reads below the barrier
    int lb = (t % 3) * 4096;
    short8 af[4], bfv[4];
#pragma unroll
    for (int i = 0; i < 4; i++) af[i] = *(const short8*)&As[lb + aoff[i]];
#pragma unroll
    for (int i = 0; i < 4; i++) bfv[i] = *(const short8*)&Bs[lb + boff[i]];
#pragma unroll
    for (int mi = 0; mi < 4; mi++)
#pragma unroll
      for (int ni = 0; ni < 4; ni++)
        acc[mi][ni] = __builtin_amdgcn_mfma_f32_16x16x32_bf16(af[mi], bfv[ni], acc[mi][ni], 0, 0, 0);
    __builtin_amdgcn_sched_barrier(0);  // keep ds_reads above the barrier
    __builtin_amdgcn_s_barrier();       // all waves done reading slot t%3
  }

#pragma unroll
  for (int mi = 0; mi < 4; mi++) {
    int rowl = wr + mi * 16 + (lane >> 4) * 4;
#pragma unroll
    for (int ni = 0; ni < 4; ni++) {
      int col = n0 + wc + ni * 16 + (lane & 15);
      float bia = bias[(size_t)e * N + col];
#pragma unroll
      for (int r = 0; r < 4; r++) {
        int gm = m0 + rowl + r;
        if (gm < cnt) {
          if constexpr (FIRST) {
            ((__hip_bfloat16*)OutP)[(size_t)(off + gm) * N + col] =
                __float2bfloat16(gelu_fast(acc[mi][ni][r] + bia));
          } else {
            ((float*)OutP)[(size_t)perm[off + gm] * N + col] = acc[mi][ni][r] + bia;
          }
        }
      }
    }
  }
}

extern "C" void kernel_launch(void* const* d_in, const int* in_sizes, int n_in,
                              void* d_out, int out_size, void* d_ws, size_t ws_size,
                              hipStream_t stream) {
  const float* x  = (const float*)d_in[0];
  const float* gw = (const float*)d_in[1];
  const float* gb = (const float*)d_in[2];
  const float* w1 = (const float*)d_in[3];
  const float* b1 = (const float*)d_in[4];
  const float* w2 = (const float*)d_in[5];
  const float* b2 = (const float*)d_in[6];
  float* out = (float*)d_out;

  char* ws = (char*)d_ws;
  int* counts = (int*)(ws + 0);
  int* fill   = (int*)(ws + 32);
  int* offs   = (int*)(ws + 64);
  int* meta   = (int*)(ws + 128);   // 145 ints
  int* eidx   = (int*)(ws + 1024);
  int* perm   = (int*)(ws + 1024 + 4 * T_TOK);
  size_t off = 1024 + 8 * (size_t)T_TOK;
  __hip_bfloat16* xb  = (__hip_bfloat16*)(ws + off); off += (size_t)T_TOK * D_DIM * 2;
  __hip_bfloat16* w1t = (__hip_bfloat16*)(ws + off); off += (size_t)E_NUM * D_DIM * F_DIM * 2;
  __hip_bfloat16* w2t = (__hip_bfloat16*)(ws + off); off += (size_t)E_NUM * D_DIM * F_DIM * 2;
  __hip_bfloat16* H   = (__hip_bfloat16*)(ws + off); off += (size_t)T_TOK * F_DIM * 2;

  hipMemsetAsync(d_ws, 0, 64, stream);  // counts + fill
  gate_kernel<<<T_TOK / 4, 256, 0, stream>>>(x, gw, gb, eidx, xb);
  count_kernel<<<T_TOK / 256, 256, 0, stream>>>(eidx, counts);
  offsets_kernel<<<1, 64, 0, stream>>>(counts, offs, meta);
  scatter_kernel<<<T_TOK / 256, 256, 0, stream>>>(eidx, offs, fill, perm);
  transpose_bf16<<<dim3(F_DIM / 64, D_DIM / 64, E_NUM), 256, 0, stream>>>(w1, w1t, D_DIM, F_DIM);
  transpose_bf16<<<dim3(D_DIM / 64, F_DIM / 64, E_NUM), 256, 0, stream>>>(w2, w2t, F_DIM, D_DIM);
  moe_gemm<D_DIM, F_DIM, true><<<8 * 9 * (F_DIM / 128), 256, 0, stream>>>(
      xb, w1t, b1, meta, offs, perm, (void*)H);
  moe_gemm<F_DIM, D_DIM, false><<<8 * 9 * (D_DIM / 128), 256, 0, stream>>>(
      H, w2t, b2, meta, offs, perm, (void*)out);
}